// Round 1
// baseline (184.959 us; speedup 1.0000x reference)
//
#include <hip/hip_runtime.h>
#include <hip/hip_bf16.h>

#define NROWS 8192
#define DIM 64

typedef __bf16 bf16x8 __attribute__((ext_vector_type(8)));
typedef float f32x4 __attribute__((ext_vector_type(4)));

// ws layout:
//   [float 0]  align_sum
//   [float 1]  S_user  (full Gram exp-sum incl. diagonal)
//   [float 2]  S_pos
//   offset 256B:          Xu bf16 [8192*64]  (1 MB)
//   offset 256B + 1MB:    Xp bf16 [8192*64]  (1 MB)

__global__ __launch_bounds__(256) void gather_norm_kernel(
    const int* __restrict__ user_id, const int* __restrict__ pos_id,
    const float* __restrict__ user_table, const float* __restrict__ item_table,
    float* __restrict__ accs,
    __hip_bfloat16* __restrict__ Xu, __hip_bfloat16* __restrict__ Xp)
{
    const int lane = threadIdx.x & 63;
    const int w    = threadIdx.x >> 6;          // wave in block, 0..3
    const int row  = blockIdx.x * 4 + w;        // one wave per batch row

    const float u = user_table[(long)user_id[row] * DIM + lane];
    const float p = item_table[(long)pos_id[row] * DIM + lane];

    float su = u * u, sp = p * p;
    #pragma unroll
    for (int m = 32; m >= 1; m >>= 1) {
        su += __shfl_xor(su, m, 64);
        sp += __shfl_xor(sp, m, 64);
    }
    const float un = u * rsqrtf(su);
    const float pn = p * rsqrtf(sp);

    Xu[row * DIM + lane] = __float2bfloat16(un);
    Xp[row * DIM + lane] = __float2bfloat16(pn);

    const float d = un - pn;
    float dd = d * d;
    #pragma unroll
    for (int m = 32; m >= 1; m >>= 1) dd += __shfl_xor(dd, m, 64);

    __shared__ float red[4];
    if (lane == 0) red[w] = dd;
    __syncthreads();
    if (threadIdx.x == 0)
        atomicAdd(&accs[0], red[0] + red[1] + red[2] + red[3]);
}

// One block computes a 128x128 tile of exp(4*sim - 4) and accumulates its sum.
// Upper-triangular tiles only (bj >= bi); off-diagonal tiles weighted 2x.
// 4 waves in 2x2; each wave computes a 64x64 sub-tile as 4x4 grid of
// 16x16x32 bf16 MFMAs (K = 64 = 2 k-steps). Fragments loaded directly from
// global (tables are L2-resident: 1 MB bf16 each).
__global__ __launch_bounds__(256) void gram_exp_kernel(
    const __hip_bfloat16* __restrict__ Xu, const __hip_bfloat16* __restrict__ Xp,
    float* __restrict__ accs)
{
    const int bi = blockIdx.x, bj = blockIdx.y;
    if (bj < bi) return;
    const __hip_bfloat16* __restrict__ X = (blockIdx.z == 0) ? Xu : Xp;

    const int tid  = threadIdx.x;
    const int lane = tid & 63;
    const int w    = tid >> 6;      // 0..3
    const int wr   = w >> 1, wc = w & 1;
    const int r    = lane & 15;     // row within 16-tile
    const int koff = (lane >> 4) * 8;  // quad*8: 8 consecutive bf16 k-values

    const int i_base = bi * 128 + wr * 64;
    const int j_base = bj * 128 + wc * 64;

    bf16x8 a[4][2], b[4][2];
    #pragma unroll
    for (int t = 0; t < 4; ++t) {
        const __hip_bfloat16* pa = X + (i_base + t * 16 + r) * DIM + koff;
        a[t][0] = *reinterpret_cast<const bf16x8*>(pa);
        a[t][1] = *reinterpret_cast<const bf16x8*>(pa + 32);
        const __hip_bfloat16* pb = X + (j_base + t * 16 + r) * DIM + koff;
        b[t][0] = *reinterpret_cast<const bf16x8*>(pb);
        b[t][1] = *reinterpret_cast<const bf16x8*>(pb + 32);
    }

    f32x4 acc[4][4];
    #pragma unroll
    for (int mt = 0; mt < 4; ++mt)
        #pragma unroll
        for (int nt = 0; nt < 4; ++nt) {
            f32x4 c = {0.f, 0.f, 0.f, 0.f};
            c = __builtin_amdgcn_mfma_f32_16x16x32_bf16(a[mt][0], b[nt][0], c, 0, 0, 0);
            c = __builtin_amdgcn_mfma_f32_16x16x32_bf16(a[mt][1], b[nt][1], c, 0, 0, 0);
            acc[mt][nt] = c;
        }

    // Epilogue: e = exp(4*sim - 4) = exp2(C4*sim - C4); sum all 64 values.
    // C/D lane->element mapping is irrelevant: we only need the tile sum.
    const float C4 = 5.770780163555851f;  // 4 * log2(e)
    float s = 0.f;
    #pragma unroll
    for (int mt = 0; mt < 4; ++mt)
        #pragma unroll
        for (int nt = 0; nt < 4; ++nt)
            #pragma unroll
            for (int e = 0; e < 4; ++e)
                s += exp2f(fmaf(C4, acc[mt][nt][e], -C4));

    #pragma unroll
    for (int m = 32; m >= 1; m >>= 1) s += __shfl_xor(s, m, 64);

    __shared__ float red[4];
    if (lane == 0) red[w] = s;
    __syncthreads();
    if (tid == 0) {
        const float wgt = (bi == bj) ? 1.f : 2.f;
        atomicAdd(&accs[1 + blockIdx.z], wgt * (red[0] + red[1] + red[2] + red[3]));
    }
}

__global__ void finalize_kernel(const float* __restrict__ accs, float* __restrict__ out)
{
    const float n = 8192.f;
    const float npairs = 8192.f * 8191.f * 0.5f;   // exact in fp32
    const float align = accs[0] / n;
    const float pu = (accs[1] - n) * 0.5f;
    const float pp = (accs[2] - n) * 0.5f;
    const float unif = 0.5f * (logf(pu / npairs) + logf(pp / npairs));
    out[0] = align + unif;   // GAMMA = 1
}

extern "C" void kernel_launch(void* const* d_in, const int* in_sizes, int n_in,
                              void* d_out, int out_size, void* d_ws, size_t ws_size,
                              hipStream_t stream)
{
    const int*   user_id    = (const int*)d_in[0];
    const int*   pos_id     = (const int*)d_in[1];
    // d_in[2] = neg_id (unused by the reference output)
    const float* user_table = (const float*)d_in[3];
    const float* item_table = (const float*)d_in[4];
    float* out  = (float*)d_out;
    float* accs = (float*)d_ws;
    __hip_bfloat16* Xu = (__hip_bfloat16*)((char*)d_ws + 256);
    __hip_bfloat16* Xp = Xu + (size_t)NROWS * DIM;

    hipMemsetAsync(d_ws, 0, 16, stream);  // zero the 3 accumulators

    gather_norm_kernel<<<NROWS / 4, 256, 0, stream>>>(
        user_id, pos_id, user_table, item_table, accs, Xu, Xp);

    gram_exp_kernel<<<dim3(NROWS / 128, NROWS / 128, 2), 256, 0, stream>>>(Xu, Xp, accs);

    finalize_kernel<<<1, 1, 0, stream>>>(accs, out);
}

// Round 2
// 133.428 us; speedup vs baseline: 1.3862x; 1.3862x over previous
//
#include <hip/hip_runtime.h>
#include <hip/hip_bf16.h>
#include <math.h>

#define NROWS 8192
#define DIM 64
#define NTILE 64          // 8192 / 128 tiles per side
#define NPAIRS 2080       // NTILE*(NTILE+1)/2 upper-triangular tile pairs

typedef __bf16 bf16x8 __attribute__((ext_vector_type(8)));
typedef float f32x4 __attribute__((ext_vector_type(4)));

// ws layout (all partials written fresh every launch; no atomics anywhere):
//   @0      : part_align float[2048]       (one per gather block)
//   @8192   : part_gram  float[2*NPAIRS]   (one per gram block, z-major)
//   @32768  : Xu bf16[8192*64]  (1 MB)
//   @32768+1MB : Xp bf16[8192*64]  (1 MB)

__global__ __launch_bounds__(256) void gather_norm_kernel(
    const int* __restrict__ user_id, const int* __restrict__ pos_id,
    const float* __restrict__ user_table, const float* __restrict__ item_table,
    float* __restrict__ part_align,
    __hip_bfloat16* __restrict__ Xu, __hip_bfloat16* __restrict__ Xp)
{
    const int lane = threadIdx.x & 63;
    const int w    = threadIdx.x >> 6;          // wave in block, 0..3
    const int row  = blockIdx.x * 4 + w;        // one wave per batch row

    const float u = user_table[(long)user_id[row] * DIM + lane];
    const float p = item_table[(long)pos_id[row] * DIM + lane];

    float su = u * u, sp = p * p;
    #pragma unroll
    for (int m = 32; m >= 1; m >>= 1) {
        su += __shfl_xor(su, m, 64);
        sp += __shfl_xor(sp, m, 64);
    }
    const float un = u * rsqrtf(su);
    const float pn = p * rsqrtf(sp);

    Xu[row * DIM + lane] = __float2bfloat16(un);
    Xp[row * DIM + lane] = __float2bfloat16(pn);

    const float d = un - pn;
    float dd = d * d;
    #pragma unroll
    for (int m = 32; m >= 1; m >>= 1) dd += __shfl_xor(dd, m, 64);

    __shared__ float red[4];
    if (lane == 0) red[w] = dd;
    __syncthreads();
    if (threadIdx.x == 0)
        part_align[blockIdx.x] = red[0] + red[1] + red[2] + red[3];  // no atomic
}

// One block per upper-triangular 128x128 tile pair (bi <= bj), decoded from a
// 1D triangular index — no dead blocks. Each block: 4 waves in 2x2, each wave
// a 64x64 sub-tile as 4x4 grid of 16x16x32 bf16 MFMAs (K=64 = 2 k-steps),
// fragments straight from global (X arrays are L2/L3-resident, 1 MB each).
// Partial tile-sum written to a distinct slot — no atomics.
__global__ __launch_bounds__(256) void gram_exp_kernel(
    const __hip_bfloat16* __restrict__ Xu, const __hip_bfloat16* __restrict__ Xp,
    float* __restrict__ part_gram)
{
    const int t = blockIdx.x;           // 0..NPAIRS-1
    const int z = blockIdx.y;           // 0 = user, 1 = pos
    const __hip_bfloat16* __restrict__ X = (z == 0) ? Xu : Xp;

    // decode lower-tri pair (i >= j): t = i*(i+1)/2 + j
    int i = (int)((sqrtf(8.0f * (float)t + 1.0f) - 1.0f) * 0.5f);
    while (i * (i + 1) / 2 > t) --i;
    while ((i + 1) * (i + 2) / 2 <= t) ++i;
    const int j = t - i * (i + 1) / 2;
    const int bi = j, bj = i;           // bi <= bj

    const int tid  = threadIdx.x;
    const int lane = tid & 63;
    const int w    = tid >> 6;          // 0..3
    const int wr   = w >> 1, wc = w & 1;
    const int r    = lane & 15;         // row within 16-tile
    const int koff = (lane >> 4) * 8;   // quad*8: 8 consecutive bf16 k-values

    const int i_base = bi * 128 + wr * 64;
    const int j_base = bj * 128 + wc * 64;

    bf16x8 a[4][2], b[4][2];
    #pragma unroll
    for (int tt = 0; tt < 4; ++tt) {
        const __hip_bfloat16* pa = X + (i_base + tt * 16 + r) * DIM + koff;
        a[tt][0] = *reinterpret_cast<const bf16x8*>(pa);
        a[tt][1] = *reinterpret_cast<const bf16x8*>(pa + 32);
        const __hip_bfloat16* pb = X + (j_base + tt * 16 + r) * DIM + koff;
        b[tt][0] = *reinterpret_cast<const bf16x8*>(pb);
        b[tt][1] = *reinterpret_cast<const bf16x8*>(pb + 32);
    }

    f32x4 acc[4][4];
    #pragma unroll
    for (int mt = 0; mt < 4; ++mt)
        #pragma unroll
        for (int nt = 0; nt < 4; ++nt) {
            f32x4 c = {0.f, 0.f, 0.f, 0.f};
            c = __builtin_amdgcn_mfma_f32_16x16x32_bf16(a[mt][0], b[nt][0], c, 0, 0, 0);
            c = __builtin_amdgcn_mfma_f32_16x16x32_bf16(a[mt][1], b[nt][1], c, 0, 0, 0);
            acc[mt][nt] = c;
        }

    // Epilogue: e = exp(4*sim - 4) = exp2(C4*sim - C4); sum all 64 values.
    // C/D lane->element mapping is irrelevant: we only need the tile sum.
    // 4 independent accumulators break the serial add chain.
    const float C4 = 5.770780163555851f;  // 4 * log2(e)
    float s0 = 0.f, s1 = 0.f, s2 = 0.f, s3 = 0.f;
    #pragma unroll
    for (int mt = 0; mt < 4; ++mt)
        #pragma unroll
        for (int nt = 0; nt < 4; ++nt) {
            s0 += __builtin_amdgcn_exp2f(fmaf(C4, acc[mt][nt][0], -C4));
            s1 += __builtin_amdgcn_exp2f(fmaf(C4, acc[mt][nt][1], -C4));
            s2 += __builtin_amdgcn_exp2f(fmaf(C4, acc[mt][nt][2], -C4));
            s3 += __builtin_amdgcn_exp2f(fmaf(C4, acc[mt][nt][3], -C4));
        }
    float s = (s0 + s1) + (s2 + s3);

    #pragma unroll
    for (int m = 32; m >= 1; m >>= 1) s += __shfl_xor(s, m, 64);

    __shared__ float red[4];
    if (lane == 0) red[w] = s;
    __syncthreads();
    if (tid == 0) {
        const float wgt = (bi == bj) ? 1.f : 2.f;
        part_gram[z * NPAIRS + t] = wgt * (red[0] + red[1] + red[2] + red[3]);
    }
}

__global__ __launch_bounds__(256) void finalize_kernel(
    const float* __restrict__ part_align, const float* __restrict__ part_gram,
    float* __restrict__ out)
{
    float a = 0.f, su = 0.f, sp = 0.f;
    for (int k = threadIdx.x; k < 2048; k += 256)   a  += part_align[k];
    for (int k = threadIdx.x; k < NPAIRS; k += 256) su += part_gram[k];
    for (int k = threadIdx.x; k < NPAIRS; k += 256) sp += part_gram[NPAIRS + k];

    #pragma unroll
    for (int m = 32; m >= 1; m >>= 1) {
        a  += __shfl_xor(a, m, 64);
        su += __shfl_xor(su, m, 64);
        sp += __shfl_xor(sp, m, 64);
    }
    __shared__ float ra[4], ru[4], rp[4];
    const int w = threadIdx.x >> 6, lane = threadIdx.x & 63;
    if (lane == 0) { ra[w] = a; ru[w] = su; rp[w] = sp; }
    __syncthreads();
    if (threadIdx.x == 0) {
        const float A  = ra[0] + ra[1] + ra[2] + ra[3];
        const float SU = ru[0] + ru[1] + ru[2] + ru[3];
        const float SP = rp[0] + rp[1] + rp[2] + rp[3];
        const float n = 8192.f;
        const float npairs = 8192.f * 8191.f * 0.5f;
        const float pu = (SU - n) * 0.5f;
        const float pp = (SP - n) * 0.5f;
        out[0] = A / n + 0.5f * (logf(pu / npairs) + logf(pp / npairs));  // GAMMA=1
    }
}

extern "C" void kernel_launch(void* const* d_in, const int* in_sizes, int n_in,
                              void* d_out, int out_size, void* d_ws, size_t ws_size,
                              hipStream_t stream)
{
    const int*   user_id    = (const int*)d_in[0];
    const int*   pos_id     = (const int*)d_in[1];
    // d_in[2] = neg_id (unused by the reference output)
    const float* user_table = (const float*)d_in[3];
    const float* item_table = (const float*)d_in[4];
    float* out = (float*)d_out;

    float* part_align = (float*)d_ws;                         // 2048 floats
    float* part_gram  = (float*)((char*)d_ws + 8192);         // 2*NPAIRS floats
    __hip_bfloat16* Xu = (__hip_bfloat16*)((char*)d_ws + 32768);
    __hip_bfloat16* Xp = Xu + (size_t)NROWS * DIM;

    gather_norm_kernel<<<NROWS / 4, 256, 0, stream>>>(
        user_id, pos_id, user_table, item_table, part_align, Xu, Xp);

    gram_exp_kernel<<<dim3(NPAIRS, 2), 256, 0, stream>>>(Xu, Xp, part_gram);

    finalize_kernel<<<1, 256, 0, stream>>>(part_align, part_gram, out);
}